// Round 4
// baseline (292.538 us; speedup 1.0000x reference)
//
#include <hip/hip_runtime.h>
#include <math.h>

#define BB   2
#define DD   192
#define LL   4096
#define KK   8
#define NN   16
#define RR   6
#define C38  38
#define CPAD 40
#define PQS  17   // per-chunk record: [S, q0..q15]; q overwritten with h0 by stitch
#define NCH  64   // chunks per channel
#define CLEN (LL / NCH)

// xdbl row layout (40 floats): [B 0..15 | C 16..31 | dts 32..37 | pad 38..39]

__device__ __forceinline__ float fexp2(float x) { return __builtin_amdgcn_exp2f(x); }
__device__ __forceinline__ float flog2(float x) { return __builtin_amdgcn_logf(x); }

__device__ __forceinline__ float softplus_f(float x) {
  return fmaxf(x, 0.f) + 0.69314718f * flog2(1.f + fexp2(-1.44269504f * fabsf(x)));
}

// xs[b,k,d,l] = x[b,d,src_index(k,l)]
__device__ __forceinline__ int src_index(int k, int l) {
  int ll = (k & 2) ? (LL - 1 - l) : l;
  int kb = k & 5;
  if (kb == 0) return ll;
  int h = ll & 63, w = ll >> 6;
  if (kb == 1) return (h << 6) + w;
  if (kb == 4) return (h << 6) + ((h + w) & 63);
  return (h << 6) + ((w - h) & 63);
}

__global__ __launch_bounds__(256) void transpose_x(const float* __restrict__ x,
                                                   float* __restrict__ xT) {
  __shared__ float tile[32][33];
  int b  = blockIdx.z;
  int p0 = blockIdx.x * 32;
  int d0 = blockIdx.y * 32;
  int tx = threadIdx.x, ty = threadIdx.y;
  #pragma unroll
  for (int i = 0; i < 32; i += 8)
    tile[ty + i][tx] = x[((size_t)(b * DD + d0 + ty + i)) * LL + p0 + tx];
  __syncthreads();
  #pragma unroll
  for (int i = 0; i < 32; i += 8)
    xT[((size_t)(b * LL + p0 + ty + i)) * DD + d0 + tx] = tile[tx][ty + i];
}

// x_dbl[b,k,l,c'] with c' = (c<6 ? 32+c : c-6); d split across 2 thread-halves
__global__ __launch_bounds__(256) void proj_kernel(const float* __restrict__ xT,
                                                   const float* __restrict__ W,
                                                   float* __restrict__ xdbl) {
  int k = blockIdx.y, b = blockIdx.z;
  int tx = threadIdx.x;
  int lloc = tx & 127, half = tx >> 7;
  int l = blockIdx.x * 128 + lloc;
  __shared__ __align__(16) float sm[DD * CPAD];  // 30720 B; reused for partials
  for (int i = tx; i < C38 * DD; i += 256) {
    int c = i / DD, dq = i - c * DD;
    int cp = (c < 6) ? (32 + c) : (c - 6);
    sm[dq * CPAD + cp] = W[(k * C38 + c) * DD + dq];
  }
  for (int dq = tx; dq < DD; dq += 256) { sm[dq * CPAD + 38] = 0.f; sm[dq * CPAD + 39] = 0.f; }
  __syncthreads();

  int p = src_index(k, l);
  const float4* xrow4 = (const float4*)(xT + ((size_t)b * LL + p) * DD) + half * 24;
  const float* wbase = sm + half * 96 * CPAD;
  float4 acc[10];
  #pragma unroll
  for (int c = 0; c < 10; ++c) acc[c] = make_float4(0.f, 0.f, 0.f, 0.f);

  for (int d4 = 0; d4 < 24; ++d4) {
    float4 xv = xrow4[d4];
    #pragma unroll
    for (int s = 0; s < 4; ++s) {
      float xs = (s == 0) ? xv.x : (s == 1) ? xv.y : (s == 2) ? xv.z : xv.w;
      const float4* w4 = (const float4*)(wbase + (d4 * 4 + s) * CPAD);
      #pragma unroll
      for (int c = 0; c < 10; ++c) {
        float4 wv = w4[c];
        acc[c].x = fmaf(wv.x, xs, acc[c].x);
        acc[c].y = fmaf(wv.y, xs, acc[c].y);
        acc[c].z = fmaf(wv.z, xs, acc[c].z);
        acc[c].w = fmaf(wv.w, xs, acc[c].w);
      }
    }
  }
  __syncthreads();  // reuse sm for partials (128*41 <= 7680)
  if (half == 1) {
    float* pr = sm + lloc * 41;
    const float* af = (const float*)acc;
    #pragma unroll
    for (int c = 0; c < 40; ++c) pr[c] = af[c];
  }
  __syncthreads();
  if (half == 0) {
    const float* pr = sm + lloc * 41;
    float* af = (float*)acc;
    #pragma unroll
    for (int c = 0; c < 40; ++c) af[c] += pr[c];
    float4* o4 = (float4*)(xdbl + ((size_t)((b * KK + k) * LL) + l) * CPAD);
    #pragma unroll
    for (int c = 0; c < 10; ++c) o4[c] = acc[c];
  }
}

// Scan: block (64,6) = one chunk, all 192 d; wave = 32 d x 2 n-halves.
// u staged in a 64x192 LDS tile (one bulk load per chunk); FINAL overwrites the
// tile with y and does one bulk coalesced atomicAdd burst (fused cross_merge).
template <bool FINAL>
__global__ __launch_bounds__(384, 4) void scan_kernel(
    const float* __restrict__ xT, const float* __restrict__ xdbl,
    const float* __restrict__ A_logs, const float* __restrict__ dtw,
    const float* __restrict__ dtb, const float* __restrict__ Ds,
    float* __restrict__ Pq, float* __restrict__ Y) {
  __shared__ float utile[CLEN * DD];  // 49152 B
  __shared__ int ptab[CLEN];
  const int lane = threadIdx.x;        // 0..63
  const int ng   = lane >> 5;          // n-half
  const int dd   = threadIdx.y;        // 0..5
  const int tid  = dd * 64 + lane;     // 0..383
  const int bk   = blockIdx.x;         // 0..15
  const int chunk = blockIdx.y;        // 0..NCH-1
  const int b = bk >> 3, k = bk & 7;
  const int d  = dd * 32 + (lane & 31);
  const int kd = k * DD + d;
  const int ch = bk * DD + d;
  const int l0 = chunk * CLEN;

  // ---- stage u tile (3072 float4 = 8 per thread) ----
  const float* xTb_base = xT + (size_t)b * LL * DD;
  if (tid < CLEN) ptab[tid] = src_index(k, l0 + tid);
  #pragma unroll
  for (int i = 0; i < 8; ++i) {
    int idx = tid + 384 * i;           // == t*48 + c4
    int t = idx / 48, c4 = idx - t * 48;
    int p = src_index(k, l0 + t);
    ((float4*)utile)[idx] = ((const float4*)(xTb_base + (size_t)p * DD))[c4];
  }

  float An2[8];
  {
    const float* ap = A_logs + (size_t)kd * NN + ng * 8;
    #pragma unroll
    for (int j = 0; j < 8; ++j) An2[j] = -__expf(ap[j]) * 1.44269504f;
  }
  float wdt[RR];
  #pragma unroll
  for (int r = 0; r < RR; ++r) wdt[r] = dtw[kd * RR + r];
  const float bias = dtb[kd];
  const float dval = FINAL ? Ds[kd] : 0.f;

  float h[8];
  if constexpr (FINAL) {
    const float* h0p = Pq + ((size_t)ch * NCH + chunk) * PQS + 1 + ng * 8;
    #pragma unroll
    for (int j = 0; j < 8; ++j) h[j] = h0p[j];
  } else {
    #pragma unroll
    for (int j = 0; j < 8; ++j) h[j] = 0.f;
  }

  const float* rowbase = xdbl + ((size_t)(bk * LL) + l0) * CPAD;

  float S = 0.f;
  float sp[2], uu[2], Bv[2][8], Cv[2][8];

  __syncthreads();

  auto LOADT = [&](int t, int s) {
    const float* row = rowbase + (size_t)t * CPAD;
    const float4* b4 = (const float4*)row + ng * 2;
    float4 bv0 = b4[0], bv1 = b4[1];
    Bv[s][0] = bv0.x; Bv[s][1] = bv0.y; Bv[s][2] = bv0.z; Bv[s][3] = bv0.w;
    Bv[s][4] = bv1.x; Bv[s][5] = bv1.y; Bv[s][6] = bv1.z; Bv[s][7] = bv1.w;
    if constexpr (FINAL) {
      const float4* c4 = (const float4*)(row + 16) + ng * 2;
      float4 cv0 = c4[0], cv1 = c4[1];
      Cv[s][0] = cv0.x; Cv[s][1] = cv0.y; Cv[s][2] = cv0.z; Cv[s][3] = cv0.w;
      Cv[s][4] = cv1.x; Cv[s][5] = cv1.y; Cv[s][6] = cv1.z; Cv[s][7] = cv1.w;
    }
    float4 dt4 = *(const float4*)(row + 32);
    float2 dt2 = *(const float2*)(row + 36);
    float dts = bias;
    dts = fmaf(dt4.x, wdt[0], dts);
    dts = fmaf(dt4.y, wdt[1], dts);
    dts = fmaf(dt4.z, wdt[2], dts);
    dts = fmaf(dt4.w, wdt[3], dts);
    dts = fmaf(dt2.x, wdt[4], dts);
    dts = fmaf(dt2.y, wdt[5], dts);
    sp[s] = softplus_f(dts);
    uu[s] = utile[t * DD + d];
  };

  auto COMPUTE = [&](int t, int s) {
    float spv = sp[s];
    float du = spv * uu[s];
    #pragma unroll
    for (int j = 0; j < 8; ++j) {
      float e = fexp2(spv * An2[j]);
      h[j] = fmaf(h[j], e, du * Bv[s][j]);
    }
    if constexpr (FINAL) {
      float y = 0.f;
      #pragma unroll
      for (int j = 0; j < 8; ++j) y = fmaf(h[j], Cv[s][j], y);
      y += __shfl_xor(y, 32, 64);
      if (ng == 0) utile[t * DD + d] = fmaf(uu[s], dval, y);
    } else {
      S += spv;
    }
  };

  LOADT(0, 0);
  for (int t = 0; t < CLEN; t += 2) {
    LOADT(t + 1, 1);
    COMPUTE(t, 0);
    int t2 = (t + 2 < CLEN) ? t + 2 : CLEN - 1;
    LOADT(t2, 0);
    COMPUTE(t + 1, 1);
  }

  if constexpr (FINAL) {
    __syncthreads();
    float* Yb = Y + (size_t)b * LL * DD;
    #pragma unroll
    for (int i = 0; i < 32; ++i) {
      int idx = tid + 384 * i;         // == t*192 + dcol
      int t = idx / DD, dcol = idx - t * DD;
      atomicAdd(&Yb[(size_t)ptab[t] * DD + dcol], utile[idx]);
    }
  } else {
    float* rec = Pq + ((size_t)ch * NCH + chunk) * PQS;
    if (ng == 0 && dd < 6) rec[0] = S;
    float* qp = rec + 1 + ng * 8;
    #pragma unroll
    for (int j = 0; j < 8; ++j) qp[j] = h[j];
  }
}

// Wave-parallel stitch: one wave per (ch, n); shuffle scan of (P,q) composition.
__global__ __launch_bounds__(256) void stitch_kernel(float* __restrict__ Pq,
                                                     const float* __restrict__ A_logs) {
  int lane = threadIdx.x & 63;
  int gw = (blockIdx.x * 256 + threadIdx.x) >> 6;  // 0..49151
  int ch = gw >> 4, n = gw & 15;
  int kd = ch % (KK * DD);
  float An2 = -__expf(A_logs[(size_t)kd * NN + n]) * 1.44269504f;

  float* rec = Pq + ((size_t)ch * NCH + lane) * PQS;
  float P = fexp2(An2 * rec[0]);
  float q = rec[1 + n];

  float Pt = P, qt = q;
  #pragma unroll
  for (int off = 1; off < 64; off <<= 1) {
    float Pp = __shfl_up(Pt, off, 64);
    float qp = __shfl_up(qt, off, 64);
    if (lane >= off) { qt = fmaf(Pt, qp, qt); Pt *= Pp; }
  }
  float hx = __shfl_up(qt, 1, 64);
  if (lane == 0) hx = 0.f;
  rec[1 + n] = hx;  // h0 for this chunk
}

__global__ __launch_bounds__(256) void ln_kernel(const float* __restrict__ Y,
                                                 const float* __restrict__ lw,
                                                 const float* __restrict__ lb,
                                                 float* __restrict__ out) {
  int lane = threadIdx.x & 63;
  int row = blockIdx.x * 4 + (threadIdx.x >> 6);
  const float* yr = Y + (size_t)row * DD;
  float v0 = yr[lane], v1 = yr[lane + 64], v2 = yr[lane + 128];
  float s1 = v0 + v1 + v2;
  float s2 = v0 * v0 + v1 * v1 + v2 * v2;
  #pragma unroll
  for (int m = 32; m >= 1; m >>= 1) {
    s1 += __shfl_xor(s1, m, 64);
    s2 += __shfl_xor(s2, m, 64);
  }
  float mu = s1 * (1.f / DD);
  float var = s2 * (1.f / DD) - mu * mu;
  float inv = rsqrtf(var + 1e-5f);
  float* orow = out + (size_t)row * DD;
  orow[lane]       = (v0 - mu) * inv * lw[lane]       + lb[lane];
  orow[lane + 64]  = (v1 - mu) * inv * lw[lane + 64]  + lb[lane + 64];
  orow[lane + 128] = (v2 - mu) * inv * lw[lane + 128] + lb[lane + 128];
}

extern "C" void kernel_launch(void* const* d_in, const int* in_sizes, int n_in,
                              void* d_out, int out_size, void* d_ws, size_t ws_size,
                              hipStream_t stream) {
  const float* x      = (const float*)d_in[0];
  const float* xpw    = (const float*)d_in[1];
  const float* dtw    = (const float*)d_in[2];
  const float* dtb    = (const float*)d_in[3];
  const float* A_logs = (const float*)d_in[4];
  const float* Ds     = (const float*)d_in[5];
  const float* ln_w   = (const float*)d_in[6];
  const float* ln_b   = (const float*)d_in[7];
  float* out = (float*)d_out;

  float* ws   = (float*)d_ws;
  float* xT   = ws;                    // B*L*D       = 1572864 floats
  float* xdbl = xT + 1572864;          // B*K*L*CPAD  = 2621440
  float* Y    = xdbl + 2621440;        // B*L*D       = 1572864
  float* Pq   = Y + 1572864;           // 3072*64*17  = 3342336

  hipMemsetAsync(Y, 0, 1572864 * sizeof(float), stream);
  transpose_x<<<dim3(LL / 32, DD / 32, BB), dim3(32, 8), 0, stream>>>(x, xT);
  proj_kernel<<<dim3(LL / 128, KK, BB), 256, 0, stream>>>(xT, xpw, xdbl);
  scan_kernel<false><<<dim3(BB * KK, NCH), dim3(64, 6), 0, stream>>>(
      xT, xdbl, A_logs, dtw, dtb, Ds, Pq, Y);
  stitch_kernel<<<(3072 * 16 * 64) / 256, 256, 0, stream>>>(Pq, A_logs);
  scan_kernel<true><<<dim3(BB * KK, NCH), dim3(64, 6), 0, stream>>>(
      xT, xdbl, A_logs, dtw, dtb, Ds, Pq, Y);
  ln_kernel<<<(BB * LL) / 4, 256, 0, stream>>>(Y, ln_w, ln_b, out);
}

// Round 5
// 279.988 us; speedup vs baseline: 1.0448x; 1.0448x over previous
//
#include <hip/hip_runtime.h>
#include <math.h>

#define BB   2
#define DD   192
#define LL   4096
#define KK   8
#define NN   16
#define RR   6
#define C38  38
#define CPAD 40
#define PQS  17   // per-chunk record: [S, q0..q15]; q overwritten with h0 by stitch
#define NCH  64   // chunks per channel
#define CLEN (LL / NCH)

// xdbl row layout (40 floats): [B 0..15 | C 16..31 | dts 32..37 | pad 38..39]

__device__ __forceinline__ float fexp2(float x) { return __builtin_amdgcn_exp2f(x); }
__device__ __forceinline__ float flog2(float x) { return __builtin_amdgcn_logf(x); }

__device__ __forceinline__ float softplus_f(float x) {
  return fmaxf(x, 0.f) + 0.69314718f * flog2(1.f + fexp2(-1.44269504f * fabsf(x)));
}

// xs[b,k,d,l] = x[b,d,src_index(k,l)]
__device__ __forceinline__ int src_index(int k, int l) {
  int ll = (k & 2) ? (LL - 1 - l) : l;
  int kb = k & 5;
  if (kb == 0) return ll;
  int h = ll & 63, w = ll >> 6;
  if (kb == 1) return (h << 6) + w;
  if (kb == 4) return (h << 6) + ((h + w) & 63);
  return (h << 6) + ((w - h) & 63);
}

__global__ __launch_bounds__(256) void transpose_x(const float* __restrict__ x,
                                                   float* __restrict__ xT) {
  __shared__ float tile[32][33];
  int b  = blockIdx.z;
  int p0 = blockIdx.x * 32;
  int d0 = blockIdx.y * 32;
  int tx = threadIdx.x, ty = threadIdx.y;
  #pragma unroll
  for (int i = 0; i < 32; i += 8)
    tile[ty + i][tx] = x[((size_t)(b * DD + d0 + ty + i)) * LL + p0 + tx];
  __syncthreads();
  #pragma unroll
  for (int i = 0; i < 32; i += 8)
    xT[((size_t)(b * LL + p0 + ty + i)) * DD + d0 + tx] = tile[tx][ty + i];
}

// x_dbl[b,k,l,c'] with c' = (c<6 ? 32+c : c-6); d split across 2 thread-halves
__global__ __launch_bounds__(256) void proj_kernel(const float* __restrict__ xT,
                                                   const float* __restrict__ W,
                                                   float* __restrict__ xdbl) {
  int k = blockIdx.y, b = blockIdx.z;
  int tx = threadIdx.x;
  int lloc = tx & 127, half = tx >> 7;
  int l = blockIdx.x * 128 + lloc;
  __shared__ __align__(16) float sm[DD * CPAD];  // 30720 B; reused for partials
  for (int i = tx; i < C38 * DD; i += 256) {
    int c = i / DD, dq = i - c * DD;
    int cp = (c < 6) ? (32 + c) : (c - 6);
    sm[dq * CPAD + cp] = W[(k * C38 + c) * DD + dq];
  }
  for (int dq = tx; dq < DD; dq += 256) { sm[dq * CPAD + 38] = 0.f; sm[dq * CPAD + 39] = 0.f; }
  __syncthreads();

  int p = src_index(k, l);
  const float4* xrow4 = (const float4*)(xT + ((size_t)b * LL + p) * DD) + half * 24;
  const float* wbase = sm + half * 96 * CPAD;
  float4 acc[10];
  #pragma unroll
  for (int c = 0; c < 10; ++c) acc[c] = make_float4(0.f, 0.f, 0.f, 0.f);

  for (int d4 = 0; d4 < 24; ++d4) {
    float4 xv = xrow4[d4];
    #pragma unroll
    for (int s = 0; s < 4; ++s) {
      float xs = (s == 0) ? xv.x : (s == 1) ? xv.y : (s == 2) ? xv.z : xv.w;
      const float4* w4 = (const float4*)(wbase + (d4 * 4 + s) * CPAD);
      #pragma unroll
      for (int c = 0; c < 10; ++c) {
        float4 wv = w4[c];
        acc[c].x = fmaf(wv.x, xs, acc[c].x);
        acc[c].y = fmaf(wv.y, xs, acc[c].y);
        acc[c].z = fmaf(wv.z, xs, acc[c].z);
        acc[c].w = fmaf(wv.w, xs, acc[c].w);
      }
    }
  }
  __syncthreads();  // reuse sm for partials (128*41 <= 7680)
  if (half == 1) {
    float* pr = sm + lloc * 41;
    const float* af = (const float*)acc;
    #pragma unroll
    for (int c = 0; c < 40; ++c) pr[c] = af[c];
  }
  __syncthreads();
  if (half == 0) {
    const float* pr = sm + lloc * 41;
    float* af = (float*)acc;
    #pragma unroll
    for (int c = 0; c < 40; ++c) af[c] += pr[c];
    float4* o4 = (float4*)(xdbl + ((size_t)((b * KK + k) * LL) + l) * CPAD);
    #pragma unroll
    for (int c = 0; c < 10; ++c) o4[c] = acc[c];
  }
}

// Scan: block (64,6) = one chunk, all 192 d; wave = 32 d x 2 n-halves.
// xdbl rows staged in LDS (10.25 KB); u prefetched via 4-deep register ring;
// sp/e/g computed in the pipelined LOAD stage so the recurrence is pure fma.
template <bool FINAL, bool MERGED>
__global__ __launch_bounds__(384, 5) void scan_kernel(
    const float* __restrict__ xT, const float* __restrict__ xdbl,
    const float* __restrict__ A_logs, const float* __restrict__ dtw,
    const float* __restrict__ dtb, const float* __restrict__ Ds,
    float* __restrict__ Pq, float* __restrict__ Y) {
  __shared__ __align__(16) float rows[CLEN * CPAD];  // 10240 B
  const int lane = threadIdx.x;        // 0..63
  const int ng   = lane >> 5;          // n-half
  const int dd   = threadIdx.y;        // 0..5
  const int tid  = dd * 64 + lane;     // 0..383
  const int bk   = blockIdx.x;         // 0..15
  const int chunk = blockIdx.y;        // 0..NCH-1
  const int b = bk >> 3, k = bk & 7;
  const int d  = dd * 32 + (lane & 31);
  const int kd = k * DD + d;
  const int ch = bk * DD + d;
  const int l0 = chunk * CLEN;

  // stage xdbl rows: 640 float4, fully coalesced
  {
    const float4* src = (const float4*)(xdbl + ((size_t)(bk * LL) + l0) * CPAD);
    float4* dst = (float4*)rows;
    #pragma unroll
    for (int i = 0; i < 2; ++i) {
      int idx = tid + 384 * i;
      if (idx < (CLEN * CPAD) / 4) dst[idx] = src[idx];
    }
  }

  const float* xTb = xT + (size_t)b * LL * DD + d;
  float uring[4];
  int   pring[4];
  #pragma unroll
  for (int i = 0; i < 4; ++i) {
    int p = src_index(k, l0 + i);
    pring[i] = p;
    uring[i] = xTb[(size_t)p * DD];
  }

  float An2[8];
  {
    const float* ap = A_logs + (size_t)kd * NN + ng * 8;
    #pragma unroll
    for (int j = 0; j < 8; ++j) An2[j] = -__expf(ap[j]) * 1.44269504f;
  }
  float wdt[RR];
  #pragma unroll
  for (int r = 0; r < RR; ++r) wdt[r] = dtw[kd * RR + r];
  const float bias = dtb[kd];
  const float dval = FINAL ? Ds[kd] : 0.f;

  float h[8];
  if constexpr (FINAL) {
    const float* h0p = Pq + ((size_t)ch * NCH + chunk) * PQS + 1 + ng * 8;
    #pragma unroll
    for (int j = 0; j < 8; ++j) h[j] = h0p[j];
  } else {
    #pragma unroll
    for (int j = 0; j < 8; ++j) h[j] = 0.f;
  }

  float S = 0.f;
  float ev[2][8], gv[2][8], Cv[2][8], uu[2];
  int   pp[2];

  __syncthreads();

  auto LOADT = [&](int t, int slot, int s) {
    const float* row = rows + t * CPAD;
    float4 dt4 = *(const float4*)(row + 32);
    float2 dt2 = *(const float2*)(row + 36);
    float dts = bias;
    dts = fmaf(dt4.x, wdt[0], dts);
    dts = fmaf(dt4.y, wdt[1], dts);
    dts = fmaf(dt4.z, wdt[2], dts);
    dts = fmaf(dt4.w, wdt[3], dts);
    dts = fmaf(dt2.x, wdt[4], dts);
    dts = fmaf(dt2.y, wdt[5], dts);
    float spv = softplus_f(dts);
    float u = uring[slot];
    int   p = pring[slot];
    int tn = t + 4;
    if (tn < CLEN) {
      int pn = src_index(k, l0 + tn);
      pring[slot] = pn;
      uring[slot] = xTb[(size_t)pn * DD];
    }
    float du = spv * u;
    float4 b0 = *(const float4*)(row + ng * 8);
    float4 b1 = *(const float4*)(row + ng * 8 + 4);
    gv[s][0] = du * b0.x; gv[s][1] = du * b0.y; gv[s][2] = du * b0.z; gv[s][3] = du * b0.w;
    gv[s][4] = du * b1.x; gv[s][5] = du * b1.y; gv[s][6] = du * b1.z; gv[s][7] = du * b1.w;
    #pragma unroll
    for (int j = 0; j < 8; ++j) ev[s][j] = fexp2(spv * An2[j]);
    if constexpr (FINAL) {
      float4 c0 = *(const float4*)(row + 16 + ng * 8);
      float4 c1 = *(const float4*)(row + 16 + ng * 8 + 4);
      Cv[s][0] = c0.x; Cv[s][1] = c0.y; Cv[s][2] = c0.z; Cv[s][3] = c0.w;
      Cv[s][4] = c1.x; Cv[s][5] = c1.y; Cv[s][6] = c1.z; Cv[s][7] = c1.w;
      uu[s] = u; pp[s] = p;
    } else {
      S += spv;
    }
  };

  auto COMPUTE = [&](int s) {
    #pragma unroll
    for (int j = 0; j < 8; ++j) h[j] = fmaf(h[j], ev[s][j], gv[s][j]);
    if constexpr (FINAL) {
      float y = 0.f;
      #pragma unroll
      for (int j = 0; j < 8; ++j) y = fmaf(h[j], Cv[s][j], y);
      y += __shfl_xor(y, 32, 64);
      if (ng == 0) {
        float outv = fmaf(uu[s], dval, y);
        if constexpr (MERGED)
          Y[((size_t)((k * BB + b) * LL) + pp[s]) * DD + d] = outv;
        else
          atomicAdd(&Y[((size_t)(b * LL) + pp[s]) * DD + d], outv);
      }
    }
  };

  LOADT(0, 0, 0);
  for (int t = 0; t < CLEN - 4; t += 4) {
    LOADT(t + 1, 1, 1); COMPUTE(0);
    LOADT(t + 2, 2, 0); COMPUTE(1);
    LOADT(t + 3, 3, 1); COMPUTE(0);
    LOADT(t + 4, 0, 0); COMPUTE(1);
  }
  LOADT(CLEN - 3, 1, 1); COMPUTE(0);
  LOADT(CLEN - 2, 2, 0); COMPUTE(1);
  LOADT(CLEN - 1, 3, 1); COMPUTE(0);
  COMPUTE(1);

  if constexpr (!FINAL) {
    float* rec = Pq + ((size_t)ch * NCH + chunk) * PQS;
    if (ng == 0) rec[0] = S;
    float* qp = rec + 1 + ng * 8;
    #pragma unroll
    for (int j = 0; j < 8; ++j) qp[j] = h[j];
  }
}

// Wave-parallel stitch: one wave per (ch, n); shuffle scan of (P,q) composition.
__global__ __launch_bounds__(256) void stitch_kernel(float* __restrict__ Pq,
                                                     const float* __restrict__ A_logs) {
  int lane = threadIdx.x & 63;
  int gw = (blockIdx.x * 256 + threadIdx.x) >> 6;  // 0..49151
  int ch = gw >> 4, n = gw & 15;
  int kd = ch % (KK * DD);
  float An2 = -__expf(A_logs[(size_t)kd * NN + n]) * 1.44269504f;

  float* rec = Pq + ((size_t)ch * NCH + lane) * PQS;
  float P = fexp2(An2 * rec[0]);
  float q = rec[1 + n];

  float Pt = P, qt = q;
  #pragma unroll
  for (int off = 1; off < 64; off <<= 1) {
    float Pp = __shfl_up(Pt, off, 64);
    float qp = __shfl_up(qt, off, 64);
    if (lane >= off) { qt = fmaf(Pt, qp, qt); Pt *= Pp; }
  }
  float hx = __shfl_up(qt, 1, 64);
  if (lane == 0) hx = 0.f;
  rec[1 + n] = hx;  // h0 for this chunk
}

// MERGED: sum 8 k-slices of Yk then LayerNorm.  Yk layout [k][b][p][d].
__global__ __launch_bounds__(256) void merge_ln_kernel(const float* __restrict__ Yk,
                                                       const float* __restrict__ lw,
                                                       const float* __restrict__ lb,
                                                       float* __restrict__ out) {
  int lane = threadIdx.x & 63;
  int row = blockIdx.x * 4 + (threadIdx.x >> 6);  // b*LL + p
  int b = row >> 12;
  float v0 = 0.f, v1 = 0.f, v2 = 0.f;
  #pragma unroll
  for (int k = 0; k < KK; ++k) {
    const float* yr = Yk + ((size_t)((k * BB + b) * LL) + (row & (LL - 1))) * DD;
    v0 += yr[lane]; v1 += yr[lane + 64]; v2 += yr[lane + 128];
  }
  float s1 = v0 + v1 + v2;
  float s2 = v0 * v0 + v1 * v1 + v2 * v2;
  #pragma unroll
  for (int m = 32; m >= 1; m >>= 1) {
    s1 += __shfl_xor(s1, m, 64);
    s2 += __shfl_xor(s2, m, 64);
  }
  float mu = s1 * (1.f / DD);
  float var = s2 * (1.f / DD) - mu * mu;
  float inv = rsqrtf(var + 1e-5f);
  float* orow = out + (size_t)row * DD;
  orow[lane]       = (v0 - mu) * inv * lw[lane]       + lb[lane];
  orow[lane + 64]  = (v1 - mu) * inv * lw[lane + 64]  + lb[lane + 64];
  orow[lane + 128] = (v2 - mu) * inv * lw[lane + 128] + lb[lane + 128];
}

__global__ __launch_bounds__(256) void ln_kernel(const float* __restrict__ Y,
                                                 const float* __restrict__ lw,
                                                 const float* __restrict__ lb,
                                                 float* __restrict__ out) {
  int lane = threadIdx.x & 63;
  int row = blockIdx.x * 4 + (threadIdx.x >> 6);
  const float* yr = Y + (size_t)row * DD;
  float v0 = yr[lane], v1 = yr[lane + 64], v2 = yr[lane + 128];
  float s1 = v0 + v1 + v2;
  float s2 = v0 * v0 + v1 * v1 + v2 * v2;
  #pragma unroll
  for (int m = 32; m >= 1; m >>= 1) {
    s1 += __shfl_xor(s1, m, 64);
    s2 += __shfl_xor(s2, m, 64);
  }
  float mu = s1 * (1.f / DD);
  float var = s2 * (1.f / DD) - mu * mu;
  float inv = rsqrtf(var + 1e-5f);
  float* orow = out + (size_t)row * DD;
  orow[lane]       = (v0 - mu) * inv * lw[lane]       + lb[lane];
  orow[lane + 64]  = (v1 - mu) * inv * lw[lane + 64]  + lb[lane + 64];
  orow[lane + 128] = (v2 - mu) * inv * lw[lane + 128] + lb[lane + 128];
}

extern "C" void kernel_launch(void* const* d_in, const int* in_sizes, int n_in,
                              void* d_out, int out_size, void* d_ws, size_t ws_size,
                              hipStream_t stream) {
  const float* x      = (const float*)d_in[0];
  const float* xpw    = (const float*)d_in[1];
  const float* dtw    = (const float*)d_in[2];
  const float* dtb    = (const float*)d_in[3];
  const float* A_logs = (const float*)d_in[4];
  const float* Ds     = (const float*)d_in[5];
  const float* ln_w   = (const float*)d_in[6];
  const float* ln_b   = (const float*)d_in[7];
  float* out = (float*)d_out;

  float* ws   = (float*)d_ws;
  float* xT   = ws;                    // 1572864 floats
  float* xdbl = xT + 1572864;          // 2621440
  float* Pq   = xdbl + 2621440;        // 3072*64*17 = 3342336
  float* Ybuf = Pq + 3342336;          // MERGED: K*B*L*D = 12582912 ; else B*L*D

  size_t need_merged = (1572864ull + 2621440 + 3342336 + 12582912) * 4;
  bool merged = ws_size >= need_merged;

  transpose_x<<<dim3(LL / 32, DD / 32, BB), dim3(32, 8), 0, stream>>>(x, xT);
  proj_kernel<<<dim3(LL / 128, KK, BB), 256, 0, stream>>>(xT, xpw, xdbl);
  scan_kernel<false, true><<<dim3(BB * KK, NCH), dim3(64, 6), 0, stream>>>(
      xT, xdbl, A_logs, dtw, dtb, Ds, Pq, Ybuf);
  stitch_kernel<<<(3072 * 16 * 64) / 256, 256, 0, stream>>>(Pq, A_logs);
  if (merged) {
    scan_kernel<true, true><<<dim3(BB * KK, NCH), dim3(64, 6), 0, stream>>>(
        xT, xdbl, A_logs, dtw, dtb, Ds, Pq, Ybuf);
    merge_ln_kernel<<<(BB * LL) / 4, 256, 0, stream>>>(Ybuf, ln_w, ln_b, out);
  } else {
    hipMemsetAsync(Ybuf, 0, 1572864 * sizeof(float), stream);
    scan_kernel<true, false><<<dim3(BB * KK, NCH), dim3(64, 6), 0, stream>>>(
        xT, xdbl, A_logs, dtw, dtb, Ds, Pq, Ybuf);
    ln_kernel<<<(BB * LL) / 4, 256, 0, stream>>>(Ybuf, ln_w, ln_b, out);
  }
}